// Round 4
// baseline (130.259 us; speedup 1.0000x reference)
//
#include <hip/hip_runtime.h>
#include <hip/hip_bf16.h>

#define IN_SIZE 65536
#define HIDDEN 128
#define D_STEPS 64
#define N_ACT 512
#define NBLK 256

typedef _Float16 half2_ __attribute__((ext_vector_type(2)));
typedef _Float16 half8_ __attribute__((ext_vector_type(8)));

__device__ __forceinline__ float dot2f(half2_ a, half2_ b, float c) {
#if __has_builtin(__builtin_amdgcn_fdot2)
    return __builtin_amdgcn_fdot2(a, b, c, false);
#else
    return c + (float)a[0] * (float)b[0] + (float)a[1] * (float)b[1];
#endif
}

// Manual grid barrier: counters zeroed per-launch by captured hipMemsetAsync.
// Co-residency guaranteed: 16-wave blocks @ <=128 VGPR -> every one of the 256
// blocks is resident (VGPR caps a CU at 16 waves, so blocks spread across CUs).
__device__ __forceinline__ void gbar(int* cnt) {
    __syncthreads();
    if (threadIdx.x == 0) {
        __hip_atomic_fetch_add(cnt, 1, __ATOMIC_RELEASE, __HIP_MEMORY_SCOPE_AGENT);
        while (__hip_atomic_load(cnt, __ATOMIC_ACQUIRE, __HIP_MEMORY_SCOPE_AGENT) < NBLK)
            __builtin_amdgcn_s_sleep(8);
    }
    __syncthreads();
}

// Phase 1: block b -> ihx rows 2b, 2b+1 (HBM-bound, 134 MB total)
// Phase 2: block 0  -> 64-step LSTM recurrence (f16 dot2, ds_read_b128 h)
// Phase 3: blocks 0..31 -> logits, 2 steps per block
__global__ __launch_bounds__(1024, 4) void fused(
    const float* __restrict__ x,
    const float* __restrict__ w_ih,
    const float* __restrict__ w_hh,
    const float* __restrict__ b_ih,
    const float* __restrict__ b_hh,
    const float* __restrict__ w_lin,
    const float* __restrict__ b_lin,
    int* __restrict__ cnt,        // cnt[0], cnt[16] barrier counters
    float* __restrict__ ihx_ws,   // 512 floats
    float* __restrict__ h_hist,   // 64*128 floats
    float* __restrict__ out) {
    int t = threadIdx.x;
    int b = blockIdx.x;

    // ---- w_hh preload for block 0 (latency hides under phase 1 + barrier) ----
    half2_ wr[HIDDEN / 2];
    int gate = t & 3;               // 0:i 1:f 2:g 3:o
    int cell = (t >> 2) & 127;
    if (b == 0 && t < 512) {
        const float2* wp2 = (const float2*)(w_hh + (size_t)(gate * HIDDEN + cell) * HIDDEN);
#pragma unroll
        for (int i = 0; i < HIDDEN / 2; ++i) {
            float2 v = wp2[i];
            half2_ w2 = {(_Float16)v.x, (_Float16)v.y};
            wr[i] = w2;
        }
    }

    // ---------------- Phase 1: ihx (2 rows per block) ----------------
    {
        int q = t >> 9;             // 0/1: which row
        int u = t & 511;
        int row = 2 * b + q;
        const float4* wp = (const float4*)(w_ih + (size_t)row * IN_SIZE);
        const float4* xp = (const float4*)x;
        float acc = 0.f;
#pragma unroll 8
        for (int i = 0; i < 32; ++i) {  // 32 x 512 float4 = 65536 floats
            float4 w4 = wp[u + i * 512];
            float4 x4 = xp[u + i * 512];
            acc += w4.x * x4.x + w4.y * x4.y + w4.z * x4.z + w4.w * x4.w;
        }
#pragma unroll
        for (int off = 32; off; off >>= 1) acc += __shfl_down(acc, off, 64);
        __shared__ float s[16];
        if ((t & 63) == 0) s[t >> 6] = acc;
        __syncthreads();
        if ((t & 511) == 0) {
            float v = 0.f;
#pragma unroll
            for (int i = 0; i < 8; ++i) v += s[(q << 3) + i];
            ihx_ws[row] = v + b_ih[row] + b_hh[row];
        }
    }
    gbar(&cnt[0]);

    // ---------------- Phase 2: recurrence (block 0 only) ----------------
    __shared__ half8_ h_v[2][HIDDEN / 8];
    if (b == 0) {
        int l = t & 63;
        float ihx = 0.f, c = 0.f;
        if (t < 512) ihx = ihx_ws[gate * HIDDEN + cell];
        if (t < HIDDEN) ((_Float16*)&h_v[0][0])[t] = (_Float16)0.f;
        __syncthreads();

        for (int d = 0; d < D_STEPS; ++d) {
            int rbuf = d & 1, wbuf = rbuf ^ 1;
            if (t < 512) {
                const half8_* hb = h_v[rbuf];
                float a0 = 0.f, a1 = 0.f, a2 = 0.f, a3 = 0.f;
#pragma unroll
                for (int i = 0; i < 16; ++i) {      // 16 x ds_read_b128, broadcast
                    union { half8_ v8; half2_ p[4]; } u;
                    u.v8 = hb[i];
                    a0 = dot2f(wr[4 * i + 0], u.p[0], a0);
                    a1 = dot2f(wr[4 * i + 1], u.p[1], a1);
                    a2 = dot2f(wr[4 * i + 2], u.p[2], a2);
                    a3 = dot2f(wr[4 * i + 3], u.p[3], a3);
                }
                float g = ihx + ((a0 + a1) + (a2 + a3));
                float kmul = (gate == 2) ? 2.f : 1.f;
                float sg = 1.f / (1.f + __expf(-kmul * g));
                float act = (gate == 2) ? (2.f * sg - 1.f) : sg;
                int base = l & ~3;
                float ai = __shfl(act, base + 0, 64);
                float af = __shfl(act, base + 1, 64);
                float at = __shfl(act, base + 2, 64);
                float ao = __shfl(act, base + 3, 64);
                c = af * c + ai * at;
                float h = ao * (2.f / (1.f + __expf(-2.f * c)) - 1.f);
                if ((t & 3) == 0) {
                    ((_Float16*)&h_v[wbuf][0])[cell] = (_Float16)h;
                    h_hist[d * HIDDEN + cell] = h;
                }
            }
            __syncthreads();
        }
    }
    gbar(&cnt[16]);

    // ---------------- Phase 3: logits (blocks 0..31, 2 steps each) -------------
    if (b < 32) {
        int s3 = t >> 9;            // 0/1: which step
        int d = 2 * b + s3;
        int n = t & 511;
        __shared__ float hs2[2][HIDDEN];
        if ((t & 511) < HIDDEN) hs2[s3][t & 127] = h_hist[d * HIDDEN + (t & 127)];
        __syncthreads();
        const float4* wp = (const float4*)(w_lin + (size_t)n * HIDDEN);
        float acc = b_lin[n];
#pragma unroll
        for (int k = 0; k < HIDDEN / 4; ++k) {
            float4 w4 = wp[k];
            acc += w4.x * hs2[s3][4 * k + 0] + w4.y * hs2[s3][4 * k + 1] +
                   w4.z * hs2[s3][4 * k + 2] + w4.w * hs2[s3][4 * k + 3];
        }
        out[d * N_ACT + n] = acc;
    }
}

extern "C" void kernel_launch(void* const* d_in, const int* in_sizes, int n_in,
                              void* d_out, int out_size, void* d_ws, size_t ws_size,
                              hipStream_t stream) {
    const float* x     = (const float*)d_in[0];
    const float* w_ih  = (const float*)d_in[1];
    const float* w_hh  = (const float*)d_in[2];
    const float* b_ih  = (const float*)d_in[3];
    const float* b_hh  = (const float*)d_in[4];
    const float* w_lin = (const float*)d_in[5];
    const float* b_lin = (const float*)d_in[6];
    float* out = (float*)d_out;

    // ws layout: [0..127] bytes: barrier counters (zeroed every call, capture-legal)
    hipMemsetAsync(d_ws, 0, 128, stream);
    int*   cnt    = (int*)d_ws;
    float* ws_f   = (float*)d_ws;
    float* ihx_ws = ws_f + 32;          // 512 floats
    float* h_hist = ws_f + 32 + 512;    // 8192 floats

    fused<<<NBLK, 1024, 0, stream>>>(x, w_ih, w_hh, b_ih, b_hh, w_lin, b_lin,
                                     cnt, ihx_ws, h_hist, out);
}

// Round 5
// 124.874 us; speedup vs baseline: 1.0431x; 1.0431x over previous
//
#include <hip/hip_runtime.h>
#include <hip/hip_bf16.h>

#define IN_SIZE 65536
#define HIDDEN 128
#define D_STEPS 64
#define N_ACT 512
#define NBLK 256

typedef _Float16 half2_ __attribute__((ext_vector_type(2)));
typedef _Float16 half8_ __attribute__((ext_vector_type(8)));

__device__ __forceinline__ float dot2f(half2_ a, half2_ b, float c) {
#if __has_builtin(__builtin_amdgcn_fdot2)
    return __builtin_amdgcn_fdot2(a, b, c, false);
#else
    return c + (float)a[0] * (float)b[0] + (float)a[1] * (float)b[1];
#endif
}

// Manual grid barrier: counters zeroed per-launch by captured hipMemsetAsync.
// Co-residency: 16-wave blocks @ waves_per_eu<=4 -> 1 block/CU -> 256 blocks on
// 256 CUs, all resident (R4 empirically confirmed the dispatcher fills slots).
__device__ __forceinline__ void gbar(int* cnt) {
    __syncthreads();
    if (threadIdx.x == 0) {
        __hip_atomic_fetch_add(cnt, 1, __ATOMIC_RELEASE, __HIP_MEMORY_SCOPE_AGENT);
        while (__hip_atomic_load(cnt, __ATOMIC_ACQUIRE, __HIP_MEMORY_SCOPE_AGENT) < NBLK)
            __builtin_amdgcn_s_sleep(8);
    }
    __syncthreads();
}

// Phase 1: block b -> ihx rows 2b, 2b+1 (HBM/L3-bound, 134 MB)
// Phase 2: block 0  -> 64-step LSTM recurrence (f16 dot2, w_hh in VGPRs)
// Phase 3: blocks 0..31 -> logits, 2 steps per block
// waves_per_eu(1,4): CAP occupancy at 4 waves/SIMD so the allocator gets the
// full 128-VGPR budget and wr[] stays in registers (R4: default heuristic went
// to 8 waves/SIMD -> 60 VGPRs -> wr spilled to scratch -> 100+us phase 2).
__global__ __attribute__((amdgpu_waves_per_eu(1, 4))) __launch_bounds__(1024)
void fused(
    const float* __restrict__ x,
    const float* __restrict__ w_ih,
    const float* __restrict__ w_hh,
    const float* __restrict__ b_ih,
    const float* __restrict__ b_hh,
    const float* __restrict__ w_lin,
    const float* __restrict__ b_lin,
    int* __restrict__ cnt,        // cnt[0], cnt[32] barrier counters
    float* __restrict__ ihx_ws,   // 512 floats
    float* __restrict__ h_hist,   // 64*128 floats
    float* __restrict__ out) {
    int t = threadIdx.x;
    int b = blockIdx.x;

    // ---- w_hh preload for block 0 (latency hides under phase 1) ----
    half2_ wr[HIDDEN / 2];
    int gate = t & 3;               // 0:i 1:f 2:g 3:o
    int cell = (t >> 2) & 127;
    if (b == 0 && t < 512) {
        const float2* wp2 = (const float2*)(w_hh + (size_t)(gate * HIDDEN + cell) * HIDDEN);
#pragma unroll
        for (int i = 0; i < HIDDEN / 2; ++i) {
            float2 v = wp2[i];
            half2_ w2 = {(_Float16)v.x, (_Float16)v.y};
            wr[i] = w2;
        }
    }

    // ---------------- Phase 1: ihx (2 rows per block) ----------------
    {
        int q = t >> 9;             // 0/1: which row
        int u = t & 511;
        int row = 2 * b + q;
        const float4* wp = (const float4*)(w_ih + (size_t)row * IN_SIZE);
        const float4* xp = (const float4*)x;
        float acc = 0.f;
#pragma unroll 4
        for (int i = 0; i < 32; ++i) {  // 32 x 512 float4 = 65536 floats
            float4 w4 = wp[u + i * 512];
            float4 x4 = xp[u + i * 512];
            acc += w4.x * x4.x + w4.y * x4.y + w4.z * x4.z + w4.w * x4.w;
        }
#pragma unroll
        for (int off = 32; off; off >>= 1) acc += __shfl_down(acc, off, 64);
        __shared__ float s[16];
        if ((t & 63) == 0) s[t >> 6] = acc;
        __syncthreads();
        if ((t & 511) == 0) {
            float v = 0.f;
#pragma unroll
            for (int i = 0; i < 8; ++i) v += s[(q << 3) + i];
            ihx_ws[row] = v + b_ih[row] + b_hh[row];
        }
    }
    gbar(&cnt[0]);

    // ---------------- Phase 2: recurrence (block 0 only) ----------------
    __shared__ half8_ h_v[2][HIDDEN / 8];
    if (b == 0) {
        int l = t & 63;
        float ihx = 0.f, c = 0.f;
        if (t < 512) ihx = ihx_ws[gate * HIDDEN + cell];
        if (t < HIDDEN) ((_Float16*)&h_v[0][0])[t] = (_Float16)0.f;
        __syncthreads();

        for (int d = 0; d < D_STEPS; ++d) {
            int rbuf = d & 1, wbuf = rbuf ^ 1;
            if (t < 512) {
                const half8_* hb = h_v[rbuf];
                float a0 = 0.f, a1 = 0.f, a2 = 0.f, a3 = 0.f;
#pragma unroll
                for (int i = 0; i < 16; ++i) {      // 16 x ds_read_b128, broadcast
                    union { half8_ v8; half2_ p[4]; } u;
                    u.v8 = hb[i];
                    a0 = dot2f(wr[4 * i + 0], u.p[0], a0);
                    a1 = dot2f(wr[4 * i + 1], u.p[1], a1);
                    a2 = dot2f(wr[4 * i + 2], u.p[2], a2);
                    a3 = dot2f(wr[4 * i + 3], u.p[3], a3);
                }
                float g = ihx + ((a0 + a1) + (a2 + a3));
                float kmul = (gate == 2) ? 2.f : 1.f;
                float sg = 1.f / (1.f + __expf(-kmul * g));
                float act = (gate == 2) ? (2.f * sg - 1.f) : sg;
                int base = l & ~3;
                float ai = __shfl(act, base + 0, 64);
                float af = __shfl(act, base + 1, 64);
                float at = __shfl(act, base + 2, 64);
                float ao = __shfl(act, base + 3, 64);
                c = af * c + ai * at;
                float h = ao * (2.f / (1.f + __expf(-2.f * c)) - 1.f);
                if ((t & 3) == 0) {
                    ((_Float16*)&h_v[wbuf][0])[cell] = (_Float16)h;
                    h_hist[d * HIDDEN + cell] = h;
                }
            }
            __syncthreads();
        }
    }
    gbar(&cnt[32]);

    // ---------------- Phase 3: logits (blocks 0..31, 2 steps each) -------------
    if (b < 32) {
        int s3 = t >> 9;            // 0/1: which step
        int d = 2 * b + s3;
        int n = t & 511;
        __shared__ float hs2[2][HIDDEN];
        if ((t & 511) < HIDDEN) hs2[s3][t & 127] = h_hist[d * HIDDEN + (t & 127)];
        __syncthreads();
        const float4* wp = (const float4*)(w_lin + (size_t)n * HIDDEN);
        float acc = b_lin[n];
#pragma unroll
        for (int k = 0; k < HIDDEN / 4; ++k) {
            float4 w4 = wp[k];
            acc += w4.x * hs2[s3][4 * k + 0] + w4.y * hs2[s3][4 * k + 1] +
                   w4.z * hs2[s3][4 * k + 2] + w4.w * hs2[s3][4 * k + 3];
        }
        out[d * N_ACT + n] = acc;
    }
}

extern "C" void kernel_launch(void* const* d_in, const int* in_sizes, int n_in,
                              void* d_out, int out_size, void* d_ws, size_t ws_size,
                              hipStream_t stream) {
    const float* x     = (const float*)d_in[0];
    const float* w_ih  = (const float*)d_in[1];
    const float* w_hh  = (const float*)d_in[2];
    const float* b_ih  = (const float*)d_in[3];
    const float* b_hh  = (const float*)d_in[4];
    const float* w_lin = (const float*)d_in[5];
    const float* b_lin = (const float*)d_in[6];
    float* out = (float*)d_out;

    // ws layout: [0..255] bytes: barrier counters (zeroed every call, capture-legal)
    hipMemsetAsync(d_ws, 0, 256, stream);
    int*   cnt    = (int*)d_ws;
    float* ws_f   = (float*)d_ws;
    float* ihx_ws = ws_f + 64;          // 512 floats
    float* h_hist = ws_f + 64 + 512;    // 8192 floats

    fused<<<NBLK, 1024, 0, stream>>>(x, w_ih, w_hh, b_ih, b_hh, w_lin, b_lin,
                                     cnt, ihx_ws, h_hist, out);
}

// Round 6
// 93.821 us; speedup vs baseline: 1.3884x; 1.3310x over previous
//
#include <hip/hip_runtime.h>
#include <hip/hip_bf16.h>

#define IN_SIZE 65536
#define HIDDEN 128
#define D_STEPS 64
#define N_ACT 512
#define NBLK 256

typedef _Float16 half2_ __attribute__((ext_vector_type(2)));
typedef _Float16 half8_ __attribute__((ext_vector_type(8)));

__device__ __forceinline__ float dot2f(half2_ a, half2_ b, float c) {
#if __has_builtin(__builtin_amdgcn_fdot2)
    return __builtin_amdgcn_fdot2(a, b, c, false);
#else
    return c + (float)a[0] * (float)b[0] + (float)a[1] * (float)b[1];
#endif
}

// Manual grid barrier; counter zeroed per-launch by captured hipMemsetAsync.
// Co-residency: 256 blocks x 8 waves @ <=256 VGPR -> >=1 block/CU on 256 CUs.
__device__ __forceinline__ void gbar(int* cnt) {
    __syncthreads();
    if (threadIdx.x == 0) {
        __hip_atomic_fetch_add(cnt, 1, __ATOMIC_RELEASE, __HIP_MEMORY_SCOPE_AGENT);
        while (__hip_atomic_load(cnt, __ATOMIC_ACQUIRE, __HIP_MEMORY_SCOPE_AGENT) < NBLK)
            __builtin_amdgcn_s_sleep(8);
    }
    __syncthreads();
}

// Phase 1: block b computes ihx rows 2b, 2b+1 (HBM-bound, 134 MB w_ih).
// Phase 2: ALL blocks run the 64-step recurrence redundantly (uniform hot path
//          -> allocator keeps wr[] in VGPRs; R4/R5: cold-branch version spilled).
//          h history kept in per-block LDS -> no 2nd grid barrier.
// Phase 3: blocks 0..63 compute logits for step d = b from their own LDS h.
__global__ __launch_bounds__(512, 1) void fused(
    const float* __restrict__ x,
    const float* __restrict__ w_ih,
    const float* __restrict__ w_hh,
    const float* __restrict__ b_ih,
    const float* __restrict__ b_hh,
    const float* __restrict__ w_lin,
    const float* __restrict__ b_lin,
    int* __restrict__ cnt,        // barrier counter
    float* __restrict__ ihx_ws,   // 512 floats
    float* __restrict__ out) {
    int t = threadIdx.x;
    int b = blockIdx.x;

    __shared__ float s[8];
    __shared__ half8_ h_v[2][HIDDEN / 8];
    __shared__ float h_all[D_STEPS][HIDDEN];   // 32 KB: full h history

    // ---------------- Phase 1: ihx (2 rows per block, half-block each) --------
    {
        int q = t >> 8;             // 0/1: which row
        int u = t & 255;
        int row = 2 * b + q;
        const float4* wp = (const float4*)(w_ih + (size_t)row * IN_SIZE);
        const float4* xp = (const float4*)x;
        float acc = 0.f;
#pragma unroll 4
        for (int i = 0; i < 64; ++i) {  // 64 x 256 float4 = 65536 floats
            float4 w4 = wp[u + i * 256];
            float4 x4 = xp[u + i * 256];
            acc += w4.x * x4.x + w4.y * x4.y + w4.z * x4.z + w4.w * x4.w;
        }
#pragma unroll
        for (int off = 32; off; off >>= 1) acc += __shfl_down(acc, off, 64);
        if ((t & 63) == 0) s[t >> 6] = acc;
        __syncthreads();
        if (t == 0)
            ihx_ws[row] = s[0] + s[1] + s[2] + s[3] + b_ih[row] + b_hh[row];
        if (t == 256)
            ihx_ws[row] = s[4] + s[5] + s[6] + s[7] + b_ih[row] + b_hh[row];
    }

    // ---- w_hh row -> 64 packed-f16 VGPRs (every block; overlaps barrier skew) --
    int gate = t & 3;               // 0:i 1:f 2:g 3:o
    int cell = t >> 2;              // 0..127
    int l = t & 63;
    half2_ wr[HIDDEN / 2];
    {
        const float2* wp2 = (const float2*)(w_hh + (size_t)(gate * HIDDEN + cell) * HIDDEN);
#pragma unroll
        for (int i = 0; i < HIDDEN / 2; ++i) {
            float2 v = wp2[i];
            half2_ w2 = {(_Float16)v.x, (_Float16)v.y};
            wr[i] = w2;
        }
    }
    gbar(cnt);

    // ---------------- Phase 2: recurrence (all blocks, redundant) -------------
    {
        float ihx = ihx_ws[gate * HIDDEN + cell];
        float c = 0.f;
        if (t < HIDDEN / 8) {
            half8_ z = {(_Float16)0.f, (_Float16)0.f, (_Float16)0.f, (_Float16)0.f,
                        (_Float16)0.f, (_Float16)0.f, (_Float16)0.f, (_Float16)0.f};
            h_v[0][t] = z;
        }
        __syncthreads();

        for (int d = 0; d < D_STEPS; ++d) {
            int rbuf = d & 1, wbuf = rbuf ^ 1;
            const half8_* hb = h_v[rbuf];
            float a0 = 0.f, a1 = 0.f, a2 = 0.f, a3 = 0.f;
#pragma unroll
            for (int i = 0; i < 16; ++i) {      // 16 x ds_read_b128, broadcast
                union { half8_ v8; half2_ p[4]; } u;
                u.v8 = hb[i];
                a0 = dot2f(wr[4 * i + 0], u.p[0], a0);
                a1 = dot2f(wr[4 * i + 1], u.p[1], a1);
                a2 = dot2f(wr[4 * i + 2], u.p[2], a2);
                a3 = dot2f(wr[4 * i + 3], u.p[3], a3);
            }
            float g = ihx + ((a0 + a1) + (a2 + a3));
            float kmul = (gate == 2) ? 2.f : 1.f;
            float sg = 1.f / (1.f + __expf(-kmul * g));
            float act = (gate == 2) ? (2.f * sg - 1.f) : sg;
            int base = l & ~3;
            float ai = __shfl(act, base + 0, 64);
            float af = __shfl(act, base + 1, 64);
            float at = __shfl(act, base + 2, 64);
            float ao = __shfl(act, base + 3, 64);
            c = af * c + ai * at;
            float h = ao * (2.f / (1.f + __expf(-2.f * c)) - 1.f);
            if ((t & 3) == 0) {
                ((_Float16*)&h_v[wbuf][0])[cell] = (_Float16)h;
                h_all[d][cell] = h;
            }
            __syncthreads();
        }
    }

    // ---------------- Phase 3: logits (blocks 0..63, own-LDS h) ---------------
    if (b < D_STEPS) {
        const float* hs = h_all[b];
        const float4* wl = (const float4*)(w_lin + (size_t)t * HIDDEN);
        float acc = b_lin[t];
#pragma unroll
        for (int k = 0; k < HIDDEN / 4; ++k) {
            float4 w4 = wl[k];
            acc += w4.x * hs[4 * k + 0] + w4.y * hs[4 * k + 1] +
                   w4.z * hs[4 * k + 2] + w4.w * hs[4 * k + 3];
        }
        out[b * N_ACT + t] = acc;
    }
}

extern "C" void kernel_launch(void* const* d_in, const int* in_sizes, int n_in,
                              void* d_out, int out_size, void* d_ws, size_t ws_size,
                              hipStream_t stream) {
    const float* x     = (const float*)d_in[0];
    const float* w_ih  = (const float*)d_in[1];
    const float* w_hh  = (const float*)d_in[2];
    const float* b_ih  = (const float*)d_in[3];
    const float* b_hh  = (const float*)d_in[4];
    const float* w_lin = (const float*)d_in[5];
    const float* b_lin = (const float*)d_in[6];
    float* out = (float*)d_out;

    // ws: [0..127] bytes barrier counter (zeroed every call, capture-legal)
    hipMemsetAsync(d_ws, 0, 128, stream);
    int*   cnt    = (int*)d_ws;
    float* ihx_ws = (float*)d_ws + 32;   // 512 floats

    fused<<<NBLK, 512, 0, stream>>>(x, w_ih, w_hh, b_ih, b_hh, w_lin, b_lin,
                                    cnt, ihx_ws, out);
}